// Round 7
// baseline (156.458 us; speedup 1.0000x reference)
//
#include <hip/hip_runtime.h>

// binary_decoder: bit-exact fp32 emulation of the reference's sequential
// carry-save adder (absmax == 0.0 verified rounds 1-6).
//
// Round-7: SYSTOLIC SKEW. Evidence: R4(13 instr/step)=60cyc, R5(9)=60,
// R6(15, dpp-slack)=84 -> per-wave cost ~ 4 cyc/instr issue cadence (+stalls);
// the R6 2-col/lane remap doubled instrs/step and regressed. So: keep the
// minimal 8-instr/step 1-col/lane mapping and remove the DPP stall by
// SKEWING: lane j runs step f at tick tau = f + j. Carry h_{j-1}(f-1) is
// produced at tau-2 -> the dpp result is consumed 2 full ticks (~60 cyc)
// later at zero added instructions. Lead-in ticks (tau < j) are naturally
// identity (bits padded 0 => a=0, c=0, s stays 0); lead-out handled by an
// 8-tick masked epilogue. Bits are packed pre-skewed (pks[g][col] bit u <->
// f = 32g+u-(col&7)); x pre-skewed into xs[b][j][tau] rows so all in-loop
// indexing is compile-time.
//
// Exactness (unchanged ops, only reordered across lanes):
//   a = bit & x == x*hard (x>=0);  uu = fp32(s+a);
//   t = fma(craw2, lsbmask, uu) == fp32(uu + c), c in {0,1} exact;
//   t in [0,4): h = floor(t*0.5) in {0,1}; s' = fma(-2,h,t) == t-2h exact.

#define F_DIM 2048
#define K_DIM 4096
#define B_DIM 8
#define G     32
#define NG    64               // main (unskewed) groups
#define NGS   65               // skewed groups incl. epilogue group
#define TROW  (NGS * G)        // 2080 ticks per xs row

#define PKS_BYTES (NGS * K_DIM * 4)        // 1,064,960
#define XS_BYTES  (B_DIM * 8 * TROW * 4)   // 532,480
#define WS_SKEW   (PKS_BYTES + XS_BYTES)   // 1,597,440
#define PK5_BYTES (64 * NG * 64 * 4)       // 1 MB (round-5 mid path)

__device__ __forceinline__ float dpp_row_shr1(float v) {
    // row_shr:1, all rows/banks, bound_ctrl: out-of-row source -> 0
    int r = __builtin_amdgcn_update_dpp(0, __float_as_int(v), 0x111, 0xf, 0xf, true);
    return __int_as_float(r);
}

__device__ __forceinline__ int sext_bit(unsigned bits, int u) {
#if __has_builtin(__builtin_amdgcn_sbfe)
    return __builtin_amdgcn_sbfe((int)bits, (unsigned)u, 1u);
#else
    return ((int)(bits << (31 - u))) >> 31;
#endif
}

// -------- pass 1a: pack pre-skewed bit planes ------------------------------
// pks[g*K_DIM + col] bit u = (w[f][col] >= 0.5) with f = 32g + u - (col&7),
// 0 <= f < F_DIM (else 0).
__global__ __launch_bounds__(64) void pack_pks(const float* __restrict__ w,
                                               unsigned* __restrict__ pks) {
    const int t    = threadIdx.x;      // 0..63 -> 4 consecutive cols
    const int slab = blockIdx.x;       // 0..15 (256 cols)
    const int g    = blockIdx.y;       // 0..64
    const int colbase = slab * 256 + t * 4;
    const float4* w4 = (const float4*)(w + colbase);

    const int j0 = (t * 4) & 7, j1 = (t * 4 + 1) & 7,
              j2 = (t * 4 + 2) & 7, j3 = (t * 4 + 3) & 7;
    unsigned b0 = 0, b1 = 0, b2 = 0, b3 = 0;
#pragma unroll
    for (int r0 = -7; r0 < 32; ++r0) {       // covers u = r0 + j for j in 0..7
        int f = g * G + r0;
        if (f >= 0 && f < F_DIM) {           // uniform per block
            float4 v = w4[f * (K_DIM / 4)];  // coalesced 1KB row slice
            unsigned u0 = (unsigned)(r0 + j0); if (u0 < 32u) b0 |= (v.x >= 0.5f ? 1u : 0u) << u0;
            unsigned u1 = (unsigned)(r0 + j1); if (u1 < 32u) b1 |= (v.y >= 0.5f ? 1u : 0u) << u1;
            unsigned u2 = (unsigned)(r0 + j2); if (u2 < 32u) b2 |= (v.z >= 0.5f ? 1u : 0u) << u2;
            unsigned u3 = (unsigned)(r0 + j3); if (u3 < 32u) b3 |= (v.w >= 0.5f ? 1u : 0u) << u3;
        }
    }
    uint4* dst = (uint4*)(pks + g * K_DIM + colbase);
    *dst = make_uint4(b0, b1, b2, b3);
}

// -------- pass 1b: skewed x table ------------------------------------------
// xs[(b*8+j)*TROW + tau] = x[b][tau-j] for tau-j in [0,F_DIM), else 0.
__global__ __launch_bounds__(256) void build_xs(const float* __restrict__ x,
                                                float* __restrict__ xs) {
    const int row = blockIdx.x;        // b*8+j, 0..63
    const int b = row >> 3, j = row & 7;
    const float* xr = x + b * F_DIM;
    float* dst = xs + row * TROW;
    for (int tau = threadIdx.x; tau < TROW; tau += 256) {
        int f = tau - j;
        dst[tau] = (f >= 0 && f < F_DIM) ? xr[f] : 0.0f;
    }
}

// -------- pass 2: skewed sequential chain ----------------------------------
__global__ __launch_bounds__(64, 1) void csa_skew(const unsigned* __restrict__ pks,
                                                  const float* __restrict__ xs,
                                                  float* __restrict__ out) {
    const int lane = threadIdx.x;                 // 0..63
    const int og   = blockIdx.x + 8 * blockIdx.y; // 0..63
    const int b    = blockIdx.z;                  // 0..7
    const int col  = og * 64 + lane;
    const int j    = lane & 7;
    const float lsbmask = (j == 0) ? 0.0f : 1.0f;

    const unsigned* pc = pks + col;                           // +K_DIM / group
    const float4*   xr = (const float4*)(xs + (b * 8 + j) * TROW);

    unsigned bb[2];
    float4   xb[2][G / 4];
#pragma unroll
    for (int p = 0; p < 2; ++p) {
        bb[p] = pc[p * K_DIM];
#pragma unroll
        for (int q = 0; q < G / 4; ++q)
            xb[p][q] = xr[p * (G / 4) + q];
    }

    float s = 0.0f;
    float craw1 = 0.0f;   // dpp(h) from previous tick
    float craw2 = 0.0f;   // dpp(h) from two ticks ago -> consumed now

    for (int g = 0; g < NG; g += 2) {       // ticks 0..2047
#pragma unroll
        for (int p = 0; p < 2; ++p) {
            const float*   xf   = (const float*)&xb[p][0];
            const unsigned bits = bb[p];
#pragma unroll
            for (int u = 0; u < G; ++u) {
                float a  = __int_as_float(sext_bit(bits, u) & __float_as_int(xf[u]));
                float uu = s + a;                         // fp32(s + a)
                float t  = __builtin_fmaf(craw2, lsbmask, uu); // fp32(uu + c)
                float hm = t * 0.5f;
                float h  = __builtin_floorf(hm);          // in {0,1}
                s = __builtin_fmaf(-2.0f, h, t);          // == t - 2h exact
                craw2 = craw1;                            // 2-tick carry delay
                craw1 = dpp_row_shr1(h);                  // consumed at +2
            }
            int gn = g + p + 2;
            int gc = (gn < NGS) ? gn : (NGS - 1);         // final slot0 = 64
            bb[p] = pc[gc * K_DIM];
#pragma unroll
            for (int q = 0; q < G / 4; ++q)
                xb[p][q] = xr[gc * (G / 4) + q];
        }
    }

    // epilogue: ticks 2048..2055 (group 64, bits 0..7). Lane j is active
    // (f = 2048+e-j < F_DIM) iff e < j; captures its final carry at e == j
    // (the value that would be consumed = h_{j-1}(f=2047), dpp'd + masked).
    const unsigned bits_e = bb[0];
    const float*   xe     = (const float*)&xb[0][0];
    float cfin = 0.0f;
#pragma unroll
    for (int e = 0; e < 8; ++e) {
        float a  = __int_as_float(sext_bit(bits_e, e) & __float_as_int(xe[e]));
        float uu = s + a;
        float t  = __builtin_fmaf(craw2, lsbmask, uu);
        float hm = t * 0.5f;
        float h  = __builtin_floorf(hm);
        float sn = __builtin_fmaf(-2.0f, h, t);
        cfin = (j == e) ? craw2 * lsbmask : cfin;
        s    = (j >  e) ? sn : s;
        craw2 = craw1;
        craw1 = dpp_row_shr1(h);
    }

    out[b * K_DIM + col]                 = s;
    out[B_DIM * K_DIM + b * K_DIM + col] = cfin;
}

// ===================== round-5 mid path (verified, 51 us) ==================
#define NBX5 4
__global__ __launch_bounds__(64) void pack_r5(const float* __restrict__ w,
                                              unsigned* __restrict__ pk) {
    const int t   = threadIdx.x;
    const int ogq = blockIdx.x;
    const int f32 = blockIdx.y;
    const float4* w4 = (const float4*)(w + ogq * 256) + t;
    unsigned b0 = 0, b1 = 0, b2 = 0, b3 = 0;
#pragma unroll
    for (int jj = 0; jj < 32; ++jj) {
        float4 v = w4[(f32 * 32 + jj) * (K_DIM / 4)];
        b0 |= (v.x >= 0.5f ? 1u : 0u) << jj;
        b1 |= (v.y >= 0.5f ? 1u : 0u) << jj;
        b2 |= (v.z >= 0.5f ? 1u : 0u) << jj;
        b3 |= (v.w >= 0.5f ? 1u : 0u) << jj;
    }
    const int og  = ogq * 4 + (t >> 4);
    const int c4  = (t & 15) * 4;
    uint4* dst = (uint4*)(pk + (og * NG + f32) * 64 + c4);
    *dst = make_uint4(b0, b1, b2, b3);
}

__global__ __launch_bounds__(64, 1) void csa_r5(const float* __restrict__ x,
                                                const unsigned* __restrict__ pk,
                                                float* __restrict__ out) {
    const int lane = threadIdx.x;
    const int og   = blockIdx.x + 8 * blockIdx.y;
    const int b    = blockIdx.z;
    const int k    = og * 64 + lane;
    const float lsbmask = ((lane & 7) == 0) ? 0.0f : 1.0f;
    int zero;
    asm volatile("v_mov_b32 %0, 0" : "=v"(zero));
    const unsigned* bp  = pk + og * (NG * 64) + lane;
    const float4*   xp4 = (const float4*)(x + b * F_DIM) + zero;
    unsigned bbuf[NBX5];
    float4   xb[NBX5][G / 4];
#pragma unroll
    for (int p = 0; p < NBX5; ++p) {
        bbuf[p] = bp[p * 64];
#pragma unroll
        for (int q = 0; q < G / 4; ++q) xb[p][q] = xp4[p * (G / 4) + q];
    }
    float s = 0.0f, craw = 0.0f;
    for (int g0 = 0; g0 < NG; g0 += NBX5) {
#pragma unroll
        for (int p = 0; p < NBX5; ++p) {
            const float*   xf   = (const float*)&xb[p][0];
            const unsigned bits = bbuf[p];
#pragma unroll
            for (int u = 0; u < G; ++u) {
                float a  = __int_as_float(sext_bit(bits, u) & __float_as_int(xf[u]));
                float uu = s + a;
                float t  = __builtin_fmaf(craw, lsbmask, uu);
                float h  = __builtin_floorf(t * 0.5f);
                s = __builtin_fmaf(-2.0f, h, t);
                craw = dpp_row_shr1(h);
            }
            int gb = g0 + p + NBX5;
            int gc = (gb < NG) ? gb : (NG - 1);
            bbuf[p] = bp[gc * 64];
#pragma unroll
            for (int q = 0; q < G / 4; ++q) xb[p][q] = xp4[gc * (G / 4) + q];
        }
    }
    out[b * K_DIM + k]                 = s;
    out[B_DIM * K_DIM + b * K_DIM + k] = craw * lsbmask;
}

// ===================== no-ws fallback ======================================
__global__ __launch_bounds__(64, 1) void csa_fallback(const float* __restrict__ x,
                                                      const float* __restrict__ weight,
                                                      float* __restrict__ out) {
    const int lane = threadIdx.x;
    const int og   = blockIdx.x + 8 * blockIdx.y;
    const int b    = blockIdx.z;
    const int k    = og * 64 + lane;
    const float lsbmask = ((lane & 7) == 0) ? 0.0f : 1.0f;
    int zero;
    asm volatile("v_mov_b32 %0, 0" : "=v"(zero));
    const float*  wp  = weight + k;
    const float4* xp4 = (const float4*)(x + b * F_DIM) + zero;
    float  wb[4][16];
    float4 xb[4][4];
#pragma unroll
    for (int p = 0; p < 4; ++p) {
#pragma unroll
        for (int u = 0; u < 16; ++u) wb[p][u] = wp[(p * 16 + u) * K_DIM];
#pragma unroll
        for (int q = 0; q < 4; ++q) xb[p][q] = xp4[p * 4 + q];
    }
    float s = 0.0f, craw = 0.0f;
    for (int f0 = 0; f0 < F_DIM; f0 += 64) {
#pragma unroll
        for (int p = 0; p < 4; ++p) {
            const float* xf = (const float*)&xb[p][0];
#pragma unroll
            for (int u = 0; u < 16; ++u) {
                float a  = (wb[p][u] >= 0.5f) ? xf[u] : 0.0f;
                float uu = s + a;
                float t  = __builtin_fmaf(craw, lsbmask, uu);
                float h  = __builtin_floorf(t * 0.5f);
                s = __builtin_fmaf(-2.0f, h, t);
                craw = dpp_row_shr1(h);
            }
            int fb = f0 + p * 16 + 64;
            int fc = (fb <= F_DIM - 16) ? fb : (F_DIM - 16);
#pragma unroll
            for (int u = 0; u < 16; ++u) wb[p][u] = wp[(fc + u) * K_DIM];
#pragma unroll
            for (int q = 0; q < 4; ++q) xb[p][q] = xp4[fc / 4 + q];
        }
    }
    out[b * K_DIM + k]                 = s;
    out[B_DIM * K_DIM + b * K_DIM + k] = craw * lsbmask;
}

extern "C" void kernel_launch(void* const* d_in, const int* in_sizes, int n_in,
                              void* d_out, int out_size, void* d_ws, size_t ws_size,
                              hipStream_t stream) {
    (void)in_sizes; (void)n_in; (void)out_size;
    const float* x      = (const float*)d_in[0];
    const float* weight = (const float*)d_in[1];
    float* out          = (float*)d_out;

    if (ws_size >= (size_t)WS_SKEW && d_ws != nullptr) {
        unsigned* pks = (unsigned*)d_ws;
        float*    xs  = (float*)((char*)d_ws + PKS_BYTES);
        pack_pks<<<dim3(16, 65, 1), dim3(64), 0, stream>>>(weight, pks);
        build_xs<<<dim3(64, 1, 1), dim3(256), 0, stream>>>(x, xs);
        csa_skew<<<dim3(8, 8, 8), dim3(64), 0, stream>>>(pks, xs, out);
    } else if (ws_size >= (size_t)PK5_BYTES && d_ws != nullptr) {
        unsigned* pk = (unsigned*)d_ws;
        pack_r5<<<dim3(16, 64, 1), dim3(64), 0, stream>>>(weight, pk);
        csa_r5<<<dim3(8, 8, 8), dim3(64), 0, stream>>>(x, pk, out);
    } else {
        csa_fallback<<<dim3(8, 8, 8), dim3(64), 0, stream>>>(x, weight, out);
    }
}

// Round 8
// 155.670 us; speedup vs baseline: 1.0051x; 1.0051x over previous
//
#include <hip/hip_runtime.h>

// binary_decoder: bit-exact fp32 emulation of the reference's sequential
// carry-save adder (absmax == 0.0 verified rounds 1-7).
//
// Round-8: CLEAN skew A/B. R7 (skew, 70us) regressed vs R5 (no skew, 51us)
// but changed 4 things at once: buffer depth 4->2, pks compact->scattered
// (FETCH 0.86->2.6MB), x addressing, skew. This round keeps R5's exact
// skeleton -- NBX=4 rotation, compact per-og pks slab [og][g][lane] (256B
// group stride), identical 8-instr step body -- with ONE semantic change:
// lane j runs step f at tick tau=f+j (inputs pre-skewed), so the dpp'd
// carry is consumed 2 ticks (~100+ cyc) after production instead of 1.
//   - If R5's ~60 cyc/step contains a dpp->consumer stall: expect 38-45 us.
//   - If neutral (~51 us): dpp edge is free; 5-level dependent s-cycle
//     (s->uu->t->hm->h->s', irreducible: the fma-fusion alternative
//     double-rounds t+a' and breaks bit-exactness) is the floor.
//
// Exactness (ops identical to R5, only lane-retimed; R7 verified absmax=0
// for this exact retiming + epilogue):
//   a = bit & x == x*hard (x>=0);  uu = fp32(s+a);
//   t = fma(c2, lsbmask, uu) == fp32(uu + c), c in {0,1} exact;
//   t in [0,4): h = floor(t*0.5) in {0,1}; s' = fma(-2,h,t) == t-2h exact.

#define F_DIM 2048
#define K_DIM 4096
#define B_DIM 8
#define G     32
#define NG    64               // main groups (2048 ticks)
#define NGS   65               // + epilogue group
#define TROW  (NGS * G)        // 2080 ticks per xs row

#define PKS_BYTES (64 * NGS * 64 * 4)      // 1,064,960  [og][g][lane]
#define XS_BYTES  (B_DIM * 8 * TROW * 4)   // 532,480    [b*8+j][tau]
#define WS_SKEW   (PKS_BYTES + XS_BYTES)
#define PK5_BYTES (64 * NG * 64 * 4)       // round-5 mid path

__device__ __forceinline__ float dpp_row_shr1(float v) {
    int r = __builtin_amdgcn_update_dpp(0, __float_as_int(v), 0x111, 0xf, 0xf, true);
    return __int_as_float(r);
}

__device__ __forceinline__ int sext_bit(unsigned bits, int u) {
#if __has_builtin(__builtin_amdgcn_sbfe)
    return __builtin_amdgcn_sbfe((int)bits, (unsigned)u, 1u);
#else
    return ((int)(bits << (31 - u))) >> 31;
#endif
}

// -------- pass 1a: pre-skewed bit planes, COMPACT per-og layout ------------
// pks[(og*NGS + g)*64 + lane] bit u = (w[f][og*64+lane] >= 0.5),
// f = 32g + u - (lane&7), 0 <= f < F_DIM (else 0).
__global__ __launch_bounds__(64) void pack_pks(const float* __restrict__ w,
                                               unsigned* __restrict__ pks) {
    const int t    = threadIdx.x;      // 0..63 -> 4 consecutive cols
    const int slab = blockIdx.x;       // 0..15 (256 cols = 4 og's)
    const int g    = blockIdx.y;       // 0..64
    const int colbase = slab * 256 + t * 4;
    const float4* w4 = (const float4*)(w + colbase);

    const int j0 = (t * 4) & 7;        // cols 4t..4t+3 -> j = j0+{0,1,2,3}
    unsigned b0 = 0, b1 = 0, b2 = 0, b3 = 0;
#pragma unroll
    for (int r0 = -7; r0 < 32; ++r0) {
        int f = g * G + r0;
        if (f >= 0 && f < F_DIM) {               // uniform per block
            float4 v = w4[f * (K_DIM / 4)];      // coalesced 1KB/row
            unsigned u0 = (unsigned)(r0 + j0 + 0); if (u0 < 32u) b0 |= (v.x >= 0.5f ? 1u : 0u) << u0;
            unsigned u1 = (unsigned)(r0 + j0 + 1); if (u1 < 32u) b1 |= (v.y >= 0.5f ? 1u : 0u) << u1;
            unsigned u2 = (unsigned)(r0 + j0 + 2); if (u2 < 32u) b2 |= (v.z >= 0.5f ? 1u : 0u) << u2;
            unsigned u3 = (unsigned)(r0 + j0 + 3); if (u3 < 32u) b3 |= (v.w >= 0.5f ? 1u : 0u) << u3;
        }
    }
    const int og = slab * 4 + (t >> 4);
    uint4* dst = (uint4*)(pks + (og * NGS + g) * 64 + (t & 15) * 4);
    *dst = make_uint4(b0, b1, b2, b3);
}

// -------- pass 1b: skewed x table ------------------------------------------
// xs[(b*8+j)*TROW + tau] = x[b][tau-j] for tau-j in [0,F_DIM), else 0.
__global__ __launch_bounds__(256) void build_xs(const float* __restrict__ x,
                                                float* __restrict__ xs) {
    const int row = blockIdx.x;        // b*8+j, 0..63
    const int b = row >> 3, j = row & 7;
    const float* xr = x + b * F_DIM;
    float* dst = xs + row * TROW;
    for (int tau = threadIdx.x; tau < TROW; tau += 256) {
        int f = tau - j;
        dst[tau] = (f >= 0 && f < F_DIM) ? xr[f] : 0.0f;
    }
}

// -------- pass 2: skewed chain, R5 skeleton --------------------------------
__global__ __launch_bounds__(64, 1) void csa_skew2(const unsigned* __restrict__ pks,
                                                   const float* __restrict__ xs,
                                                   float* __restrict__ out) {
    const int lane = threadIdx.x;                 // 0..63
    const int og   = blockIdx.x + 8 * blockIdx.y; // 0..63
    const int b    = blockIdx.z;                  // 0..7
    const int col  = og * 64 + lane;
    const int j    = lane & 7;
    const float lsbmask = (j == 0) ? 0.0f : 1.0f;

    const unsigned* pc = pks + og * (NGS * 64) + lane;     // +64 per group
    const float4*   xr = (const float4*)(xs + (b * 8 + j) * TROW);

    unsigned bb[4];
    float4   xb[4][G / 4];
#pragma unroll
    for (int p = 0; p < 4; ++p) {
        bb[p] = pc[p * 64];
#pragma unroll
        for (int q = 0; q < G / 4; ++q)
            xb[p][q] = xr[p * (G / 4) + q];
    }

    float s = 0.0f;
    float c1 = 0.0f;   // dpp(h) from previous tick
    float c2 = 0.0f;   // dpp(h) from two ticks ago -> consumed now

    for (int g0 = 0; g0 < NG; g0 += 4) {       // ticks 0..2047
#pragma unroll
        for (int p = 0; p < 4; ++p) {
            const float*   xf   = (const float*)&xb[p][0];
            const unsigned bits = bb[p];
#pragma unroll
            for (int u = 0; u < G; ++u) {
                float a  = __int_as_float(sext_bit(bits, u) & __float_as_int(xf[u]));
                float uu = s + a;                          // fp32(s + a)
                float t  = __builtin_fmaf(c2, lsbmask, uu); // fp32(uu + c)
                float hm = t * 0.5f;
                float h  = __builtin_floorf(hm);           // in {0,1}
                s = __builtin_fmaf(-2.0f, h, t);           // == t - 2h exact
                c2 = c1;                                   // 2-tick delay
                c1 = dpp_row_shr1(h);                      // consumed at +2
            }
            int gn = g0 + p + 4;
            int gc = (gn < NGS) ? gn : (NGS - 1);          // ends at group 64
            bb[p] = pc[gc * 64];
#pragma unroll
            for (int q = 0; q < G / 4; ++q)
                xb[p][q] = xr[gc * (G / 4) + q];
        }
    }

    // epilogue: ticks 2048..2055 (group 64). Lane j still active iff e < j;
    // captures its final carry at e == j. Verified absmax=0 in round 7.
    const unsigned bits_e = bb[0];
    const float*   xe     = (const float*)&xb[0][0];
    float cfin = 0.0f;
#pragma unroll
    for (int e = 0; e < 8; ++e) {
        float a  = __int_as_float(sext_bit(bits_e, e) & __float_as_int(xe[e]));
        float uu = s + a;
        float t  = __builtin_fmaf(c2, lsbmask, uu);
        float hm = t * 0.5f;
        float h  = __builtin_floorf(hm);
        float sn = __builtin_fmaf(-2.0f, h, t);
        cfin = (j == e) ? c2 * lsbmask : cfin;
        s    = (j >  e) ? sn : s;
        c2 = c1;
        c1 = dpp_row_shr1(h);
    }

    out[b * K_DIM + col]                 = s;
    out[B_DIM * K_DIM + b * K_DIM + col] = cfin;
}

// ===================== round-5 mid path (verified, 51 us) ==================
__global__ __launch_bounds__(64) void pack_r5(const float* __restrict__ w,
                                              unsigned* __restrict__ pk) {
    const int t   = threadIdx.x;
    const int ogq = blockIdx.x;
    const int f32 = blockIdx.y;
    const float4* w4 = (const float4*)(w + ogq * 256) + t;
    unsigned b0 = 0, b1 = 0, b2 = 0, b3 = 0;
#pragma unroll
    for (int jj = 0; jj < 32; ++jj) {
        float4 v = w4[(f32 * 32 + jj) * (K_DIM / 4)];
        b0 |= (v.x >= 0.5f ? 1u : 0u) << jj;
        b1 |= (v.y >= 0.5f ? 1u : 0u) << jj;
        b2 |= (v.z >= 0.5f ? 1u : 0u) << jj;
        b3 |= (v.w >= 0.5f ? 1u : 0u) << jj;
    }
    const int og = ogq * 4 + (t >> 4);
    uint4* dst = (uint4*)(pk + (og * NG + f32) * 64 + (t & 15) * 4);
    *dst = make_uint4(b0, b1, b2, b3);
}

__global__ __launch_bounds__(64, 1) void csa_r5(const float* __restrict__ x,
                                                const unsigned* __restrict__ pk,
                                                float* __restrict__ out) {
    const int lane = threadIdx.x;
    const int og   = blockIdx.x + 8 * blockIdx.y;
    const int b    = blockIdx.z;
    const int k    = og * 64 + lane;
    const float lsbmask = ((lane & 7) == 0) ? 0.0f : 1.0f;
    int zero;
    asm volatile("v_mov_b32 %0, 0" : "=v"(zero));
    const unsigned* bp  = pk + og * (NG * 64) + lane;
    const float4*   xp4 = (const float4*)(x + b * F_DIM) + zero;
    unsigned bbuf[4];
    float4   xb[4][G / 4];
#pragma unroll
    for (int p = 0; p < 4; ++p) {
        bbuf[p] = bp[p * 64];
#pragma unroll
        for (int q = 0; q < G / 4; ++q) xb[p][q] = xp4[p * (G / 4) + q];
    }
    float s = 0.0f, craw = 0.0f;
    for (int g0 = 0; g0 < NG; g0 += 4) {
#pragma unroll
        for (int p = 0; p < 4; ++p) {
            const float*   xf   = (const float*)&xb[p][0];
            const unsigned bits = bbuf[p];
#pragma unroll
            for (int u = 0; u < G; ++u) {
                float a  = __int_as_float(sext_bit(bits, u) & __float_as_int(xf[u]));
                float uu = s + a;
                float t  = __builtin_fmaf(craw, lsbmask, uu);
                float h  = __builtin_floorf(t * 0.5f);
                s = __builtin_fmaf(-2.0f, h, t);
                craw = dpp_row_shr1(h);
            }
            int gb = g0 + p + 4;
            int gc = (gb < NG) ? gb : (NG - 1);
            bbuf[p] = bp[gc * 64];
#pragma unroll
            for (int q = 0; q < G / 4; ++q) xb[p][q] = xp4[gc * (G / 4) + q];
        }
    }
    out[b * K_DIM + k]                 = s;
    out[B_DIM * K_DIM + b * K_DIM + k] = craw * lsbmask;
}

// ===================== no-ws fallback ======================================
__global__ __launch_bounds__(64, 1) void csa_fallback(const float* __restrict__ x,
                                                      const float* __restrict__ weight,
                                                      float* __restrict__ out) {
    const int lane = threadIdx.x;
    const int og   = blockIdx.x + 8 * blockIdx.y;
    const int b    = blockIdx.z;
    const int k    = og * 64 + lane;
    const float lsbmask = ((lane & 7) == 0) ? 0.0f : 1.0f;
    int zero;
    asm volatile("v_mov_b32 %0, 0" : "=v"(zero));
    const float*  wp  = weight + k;
    const float4* xp4 = (const float4*)(x + b * F_DIM) + zero;
    float  wb[4][16];
    float4 xb[4][4];
#pragma unroll
    for (int p = 0; p < 4; ++p) {
#pragma unroll
        for (int u = 0; u < 16; ++u) wb[p][u] = wp[(p * 16 + u) * K_DIM];
#pragma unroll
        for (int q = 0; q < 4; ++q) xb[p][q] = xp4[p * 4 + q];
    }
    float s = 0.0f, craw = 0.0f;
    for (int f0 = 0; f0 < F_DIM; f0 += 64) {
#pragma unroll
        for (int p = 0; p < 4; ++p) {
            const float* xf = (const float*)&xb[p][0];
#pragma unroll
            for (int u = 0; u < 16; ++u) {
                float a  = (wb[p][u] >= 0.5f) ? xf[u] : 0.0f;
                float uu = s + a;
                float t  = __builtin_fmaf(craw, lsbmask, uu);
                float h  = __builtin_floorf(t * 0.5f);
                s = __builtin_fmaf(-2.0f, h, t);
                craw = dpp_row_shr1(h);
            }
            int fb = f0 + p * 16 + 64;
            int fc = (fb <= F_DIM - 16) ? fb : (F_DIM - 16);
#pragma unroll
            for (int u = 0; u < 16; ++u) wb[p][u] = wp[(fc + u) * K_DIM];
#pragma unroll
            for (int q = 0; q < 4; ++q) xb[p][q] = xp4[fc / 4 + q];
        }
    }
    out[b * K_DIM + k]                 = s;
    out[B_DIM * K_DIM + b * K_DIM + k] = craw * lsbmask;
}

extern "C" void kernel_launch(void* const* d_in, const int* in_sizes, int n_in,
                              void* d_out, int out_size, void* d_ws, size_t ws_size,
                              hipStream_t stream) {
    (void)in_sizes; (void)n_in; (void)out_size;
    const float* x      = (const float*)d_in[0];
    const float* weight = (const float*)d_in[1];
    float* out          = (float*)d_out;

    if (ws_size >= (size_t)WS_SKEW && d_ws != nullptr) {
        unsigned* pks = (unsigned*)d_ws;
        float*    xs  = (float*)((char*)d_ws + PKS_BYTES);
        pack_pks<<<dim3(16, 65, 1), dim3(64), 0, stream>>>(weight, pks);
        build_xs<<<dim3(64, 1, 1), dim3(256), 0, stream>>>(x, xs);
        csa_skew2<<<dim3(8, 8, 8), dim3(64), 0, stream>>>(pks, xs, out);
    } else if (ws_size >= (size_t)PK5_BYTES && d_ws != nullptr) {
        unsigned* pk = (unsigned*)d_ws;
        pack_r5<<<dim3(16, 64, 1), dim3(64), 0, stream>>>(weight, pk);
        csa_r5<<<dim3(8, 8, 8), dim3(64), 0, stream>>>(x, pk, out);
    } else {
        csa_fallback<<<dim3(8, 8, 8), dim3(64), 0, stream>>>(x, weight, out);
    }
}

// Round 9
// 125.443 us; speedup vs baseline: 1.2472x; 1.2410x over previous
//
#include <hip/hip_runtime.h>

// binary_decoder: bit-exact fp32 emulation of the reference's sequential
// carry-save adder (absmax == 0.0 verified rounds 1-8).
//
// Round-9: HALF-SCALED CHAIN, 5 -> 3 dependent levels.
// Model (fits R4/R5 exactly, survived the R8 skew A/B): wall = 2048 steps x
// (chain levels) x ~12 cyc lone-wave dependent-VALU latency. R5's s-cycle
// add->fma->mul->floor->fma = 5 levels = 60 cyc/step = 51.2 us. Fix: keep
// state scaled by 1/2 (S = s/2, A = (x/2)&bit, C = h/2). Power-of-two
// scaling commutes with IEEE rounding (all values are multiples of 2^-24 in
// [0,4) -- no denormals/overflow), so:
//   U = S + A        == fp32(s+a)/2   exactly
//   T = fma(craw, halfmask, U) == fp32(t)/2 exactly (craw*halfmask in {0,.5})
//   h = floor(T)     == floor(t/2)    (the *0.5 vanished into the state)
//   S' = fract(T)    == (t - 2h)/2    exactly (v_fract exact on [0,2))
// s-cycle: add -> fma -> fract = 3 levels; carry cycle T->floor->dpp->fma
// also 3. Predicted 36-44 cyc/step -> 31-38 us. x*0.5 and the bit-AND are
// off the chain. Outputs: s = S+S (exact), c = dpp(h)*lsbmask, h in {0,1}.

#define F_DIM 2048
#define K_DIM 4096
#define B_DIM 8
#define G     32
#define NG    64
#define PK_BYTES (64 * NG * 64 * 4)   // 1 MB compact [og][g][lane]

__device__ __forceinline__ float dpp_row_shr1(float v) {
    // row_shr:1, all rows/banks, bound_ctrl: out-of-row source -> 0
    int r = __builtin_amdgcn_update_dpp(0, __float_as_int(v), 0x111, 0xf, 0xf, true);
    return __int_as_float(r);
}

__device__ __forceinline__ int sext_bit(unsigned bits, int u) {
#if __has_builtin(__builtin_amdgcn_sbfe)
    return __builtin_amdgcn_sbfe((int)bits, (unsigned)u, 1u);
#else
    return ((int)(bits << (31 - u))) >> 31;
#endif
}

__device__ __forceinline__ float fract_f32(float v) {
#if __has_builtin(__builtin_amdgcn_fractf)
    return __builtin_amdgcn_fractf(v);        // v_fract_f32: v - floor(v), exact
#else
    return v - __builtin_floorf(v);           // 4-level fallback, still < 5
#endif
}

// -------- pass 1: pack (w >= 0.5) bits, compact per-og layout --------------
// pk[(og*NG + g)*64 + lane] bit u = (w[32g+u][og*64+lane] >= 0.5)
__global__ __launch_bounds__(64) void pack_r5(const float* __restrict__ w,
                                              unsigned* __restrict__ pk) {
    const int t   = threadIdx.x;       // 0..63 -> 4 consecutive cols
    const int ogq = blockIdx.x;        // 0..15 (256-col slab)
    const int f32 = blockIdx.y;        // 0..63
    const float4* w4 = (const float4*)(w + ogq * 256) + t;
    unsigned b0 = 0, b1 = 0, b2 = 0, b3 = 0;
#pragma unroll
    for (int jj = 0; jj < 32; ++jj) {
        float4 v = w4[(f32 * 32 + jj) * (K_DIM / 4)];   // coalesced 1KB/row
        b0 |= (v.x >= 0.5f ? 1u : 0u) << jj;
        b1 |= (v.y >= 0.5f ? 1u : 0u) << jj;
        b2 |= (v.z >= 0.5f ? 1u : 0u) << jj;
        b3 |= (v.w >= 0.5f ? 1u : 0u) << jj;
    }
    const int og = ogq * 4 + (t >> 4);
    uint4* dst = (uint4*)(pk + (og * NG + f32) * 64 + (t & 15) * 4);
    *dst = make_uint4(b0, b1, b2, b3);
}

// -------- pass 2: half-scaled sequential chain -----------------------------
__global__ __launch_bounds__(64, 1) void csa_v9(const float* __restrict__ x,
                                                const unsigned* __restrict__ pk,
                                                float* __restrict__ out) {
    const int lane = threadIdx.x;                 // 0..63
    const int og   = blockIdx.x + 8 * blockIdx.y; // 0..63
    const int b    = blockIdx.z;                  // 0..7
    const int k    = og * 64 + lane;
    const int j    = lane & 7;

    const float lsbmask  = (j == 0) ? 0.0f : 1.0f;  // final carry output mask
    const float halfmask = (j == 0) ? 0.0f : 0.5f;  // C = h/2 carry-in weight

    // Opaque zero: keep the x address out of the SMEM (lgkmcnt) domain.
    int zero;
    asm volatile("v_mov_b32 %0, 0" : "=v"(zero));

    const unsigned* bp  = pk + og * (NG * 64) + lane;       // +64 per group
    const float4*   xp4 = (const float4*)(x + b * F_DIM) + zero;

    unsigned bbuf[4];
    float4   xb[4][G / 4];
#pragma unroll
    for (int p = 0; p < 4; ++p) {
        bbuf[p] = bp[p * 64];
#pragma unroll
        for (int q = 0; q < G / 4; ++q) xb[p][q] = xp4[p * (G / 4) + q];
    }

    float S = 0.0f;       // s/2, exactly
    float craw = 0.0f;    // dpp(h) from previous step, h in {0,1}

    for (int g0 = 0; g0 < NG; g0 += 4) {
#pragma unroll
        for (int p = 0; p < 4; ++p) {
            const float*   xf   = (const float*)&xb[p][0];
            const unsigned bits = bbuf[p];
#pragma unroll
            for (int u = 0; u < G; ++u) {
                // off-chain: A = (x/2) & bit  (x/2 exact: x normal, >= 2^-23)
                float xh = xf[u] * 0.5f;
                float A  = __int_as_float(sext_bit(bits, u) & __float_as_int(xh));
                // 3-level dependent cycle:
                float U = S + A;                              // fp32(s+a)/2
                float T = __builtin_fmaf(craw, halfmask, U);  // fp32(t)/2
                float h = __builtin_floorf(T);                // floor(t/2), off s-cycle
                S = fract_f32(T);                             // (t-2h)/2 exact
                craw = dpp_row_shr1(h);                       // carry to MSB lane
            }
            int gb = g0 + p + 4;
            int gc = (gb < NG) ? gb : (NG - 1);
            bbuf[p] = bp[gc * 64];
#pragma unroll
            for (int q = 0; q < G / 4; ++q) xb[p][q] = xp4[gc * (G / 4) + q];
        }
    }

    out[b * K_DIM + k]                 = S + S;          // s = 2S, exact
    out[B_DIM * K_DIM + b * K_DIM + k] = craw * lsbmask; // final carry
}

// -------- no-ws fallback (round-5 chain, verified) -------------------------
__global__ __launch_bounds__(64, 1) void csa_fallback(const float* __restrict__ x,
                                                      const float* __restrict__ weight,
                                                      float* __restrict__ out) {
    const int lane = threadIdx.x;
    const int og   = blockIdx.x + 8 * blockIdx.y;
    const int b    = blockIdx.z;
    const int k    = og * 64 + lane;
    const float lsbmask = ((lane & 7) == 0) ? 0.0f : 1.0f;
    int zero;
    asm volatile("v_mov_b32 %0, 0" : "=v"(zero));
    const float*  wp  = weight + k;
    const float4* xp4 = (const float4*)(x + b * F_DIM) + zero;
    float  wb[4][16];
    float4 xb[4][4];
#pragma unroll
    for (int p = 0; p < 4; ++p) {
#pragma unroll
        for (int u = 0; u < 16; ++u) wb[p][u] = wp[(p * 16 + u) * K_DIM];
#pragma unroll
        for (int q = 0; q < 4; ++q) xb[p][q] = xp4[p * 4 + q];
    }
    float s = 0.0f, craw = 0.0f;
    for (int f0 = 0; f0 < F_DIM; f0 += 64) {
#pragma unroll
        for (int p = 0; p < 4; ++p) {
            const float* xf = (const float*)&xb[p][0];
#pragma unroll
            for (int u = 0; u < 16; ++u) {
                float a  = (wb[p][u] >= 0.5f) ? xf[u] : 0.0f;
                float uu = s + a;
                float t  = __builtin_fmaf(craw, lsbmask, uu);
                float h  = __builtin_floorf(t * 0.5f);
                s = __builtin_fmaf(-2.0f, h, t);
                craw = dpp_row_shr1(h);
            }
            int fb = f0 + p * 16 + 64;
            int fc = (fb <= F_DIM - 16) ? fb : (F_DIM - 16);
#pragma unroll
            for (int u = 0; u < 16; ++u) wb[p][u] = wp[(fc + u) * K_DIM];
#pragma unroll
            for (int q = 0; q < 4; ++q) xb[p][q] = xp4[fc / 4 + q];
        }
    }
    out[b * K_DIM + k]                 = s;
    out[B_DIM * K_DIM + b * K_DIM + k] = craw * lsbmask;
}

extern "C" void kernel_launch(void* const* d_in, const int* in_sizes, int n_in,
                              void* d_out, int out_size, void* d_ws, size_t ws_size,
                              hipStream_t stream) {
    (void)in_sizes; (void)n_in; (void)out_size;
    const float* x      = (const float*)d_in[0];
    const float* weight = (const float*)d_in[1];
    float* out          = (float*)d_out;

    if (ws_size >= (size_t)PK_BYTES && d_ws != nullptr) {
        unsigned* pk = (unsigned*)d_ws;
        pack_r5<<<dim3(16, 64, 1), dim3(64), 0, stream>>>(weight, pk);
        csa_v9<<<dim3(8, 8, 8), dim3(64), 0, stream>>>(x, pk, out);
    } else {
        csa_fallback<<<dim3(8, 8, 8), dim3(64), 0, stream>>>(x, weight, out);
    }
}